// Round 1
// baseline (170.353 us; speedup 1.0000x reference)
//
#include <hip/hip_runtime.h>
#include <hip/hip_bf16.h>

#define M_ROWS 8192
#define HALF_N 4096
#define D 128
#define INV_T 2.0f   // 1 / temperature(0.5)

typedef __attribute__((ext_vector_type(4))) float f32x4;
typedef __attribute__((ext_vector_type(8))) short bf16x8;
typedef unsigned int u32;
typedef __attribute__((ext_vector_type(4))) u32 u32x4;

// ---------------------------------------------------------------------------
// Kernel A: L2-normalize rows (fp32 in, bf16 out), zero accumulators.
// One wave (64 lanes) per row; lane handles 2 of the 128 elements.
// ---------------------------------------------------------------------------
__global__ __launch_bounds__(256) void k_normalize(
    const float* __restrict__ zi, const float* __restrict__ zj,
    __hip_bfloat16* __restrict__ zb, float* __restrict__ rowsum,
    float* __restrict__ lossacc)
{
    int t = blockIdx.x * 256 + threadIdx.x;
    if (t < M_ROWS) rowsum[t] = 0.0f;   // re-init every launch (ws not re-poisoned)
    if (t == 0) lossacc[0] = 0.0f;

    int row  = t >> 6;
    int lane = t & 63;
    const float* src = (row < HALF_N) ? (zi + (size_t)row * D)
                                      : (zj + (size_t)(row - HALF_N) * D);
    float2 v = *(const float2*)(src + lane * 2);
    float ss = v.x * v.x + v.y * v.y;
    #pragma unroll
    for (int o = 32; o >= 1; o >>= 1) ss += __shfl_xor(ss, o);
    float scale = 1.0f / fmaxf(sqrtf(ss), 1e-12f);

    __hip_bfloat162 o2;
    o2.x = __float2bfloat16(v.x * scale);
    o2.y = __float2bfloat16(v.y * scale);
    *(__hip_bfloat162*)(zb + (size_t)row * D + lane * 2) = o2;
}

// ---------------------------------------------------------------------------
// Kernel B: for each 128x128 tile of sim = (zb zb^T)/T, accumulate
// rowsum[i] += sum_j exp(sim[i][j]) via fp32 atomics. Diagonal included
// (subtracted exactly in kernel C).
// 256 threads = 4 waves; wave w owns rows [32w, 32w+32) x all 128 cols.
// LDS: A,B tiles 32KB each, XOR-swizzled 16B slots to kill bank conflicts.
// ---------------------------------------------------------------------------
__global__ __launch_bounds__(256) void k_simsum(
    const __hip_bfloat16* __restrict__ zb, float* __restrict__ rowsum)
{
    __shared__ u32x4 smem[4096];            // 64 KiB
    char* sA = (char*)smem;                 // [128 rows][256 B]
    char* sB = (char*)(smem + 2048);

    const int ibase = blockIdx.y * 128;
    const int jbase = blockIdx.x * 128;
    const int tid   = threadIdx.x;

    // Stage both tiles: 2048 chunks of 16B each per tile; swizzle slot ^= row&7.
    #pragma unroll
    for (int it = 0; it < 8; ++it) {
        int c = it * 256 + tid;
        int row = c >> 4, slot = c & 15;
        int dst = row * 256 + ((slot ^ (row & 7)) << 4);
        u32x4 va = *(const u32x4*)(zb + (size_t)(ibase + row) * D + slot * 8);
        *(u32x4*)(sA + dst) = va;
        u32x4 vb = *(const u32x4*)(zb + (size_t)(jbase + row) * D + slot * 8);
        *(u32x4*)(sB + dst) = vb;
    }
    __syncthreads();

    const int wv = tid >> 6, lane = tid & 63;
    const int lr = lane & 15, lg = lane >> 4;
    const int rbase = wv * 32;

    f32x4 acc[2][8];
    #pragma unroll
    for (int m = 0; m < 2; ++m)
        #pragma unroll
        for (int n = 0; n < 8; ++n) acc[m][n] = (f32x4){0.f, 0.f, 0.f, 0.f};

    #pragma unroll
    for (int ks = 0; ks < 4; ++ks) {
        int rowA0 = rbase + lr;
        int rowA1 = rbase + 16 + lr;
        bf16x8 a0 = *(const bf16x8*)(sA + rowA0 * 256 + (((ks * 4 + lg) ^ (rowA0 & 7)) << 4));
        bf16x8 a1 = *(const bf16x8*)(sA + rowA1 * 256 + (((ks * 4 + lg) ^ (rowA1 & 7)) << 4));
        #pragma unroll
        for (int n = 0; n < 8; ++n) {
            int rowB = n * 16 + lr;
            bf16x8 b = *(const bf16x8*)(sB + rowB * 256 + (((ks * 4 + lg) ^ (rowB & 7)) << 4));
            acc[0][n] = __builtin_amdgcn_mfma_f32_16x16x32_bf16(a0, b, acc[0][n], 0, 0, 0);
            acc[1][n] = __builtin_amdgcn_mfma_f32_16x16x32_bf16(a1, b, acc[1][n], 0, 0, 0);
        }
    }

    // Epilogue: exp(2*dot), reduce over 16 col-lanes, one atomic per row.
    #pragma unroll
    for (int m = 0; m < 2; ++m) {
        #pragma unroll
        for (int r = 0; r < 4; ++r) {
            float e = 0.f;
            #pragma unroll
            for (int n = 0; n < 8; ++n) e += __expf(INV_T * acc[m][n][r]);
            e += __shfl_xor(e, 1);
            e += __shfl_xor(e, 2);
            e += __shfl_xor(e, 4);
            e += __shfl_xor(e, 8);
            if (lr == 0) {
                int row = ibase + rbase + m * 16 + lg * 4 + r;
                atomicAdd(&rowsum[row], e);
            }
        }
    }
}

// ---------------------------------------------------------------------------
// Kernel C: per row, recompute self-dot and positive-pair dot (fp32 from
// bf16), lse = log(rowsum - exp(2*self) + exp(2*pos)), accumulate lse - pos.
// One wave per row.
// ---------------------------------------------------------------------------
__global__ __launch_bounds__(256) void k_rowloss(
    const __hip_bfloat16* __restrict__ zb, const float* __restrict__ rowsum,
    float* __restrict__ lossacc)
{
    int t = blockIdx.x * 256 + threadIdx.x;
    int row = t >> 6, lane = t & 63;
    int pair = row ^ HALF_N;

    __hip_bfloat162 av = *(const __hip_bfloat162*)(zb + (size_t)row  * D + lane * 2);
    __hip_bfloat162 bv = *(const __hip_bfloat162*)(zb + (size_t)pair * D + lane * 2);
    float ax = __bfloat162float(av.x), ay = __bfloat162float(av.y);
    float bx = __bfloat162float(bv.x), by = __bfloat162float(bv.y);
    float sd = ax * ax + ay * ay;
    float pd = ax * bx + ay * by;
    #pragma unroll
    for (int o = 32; o >= 1; o >>= 1) {
        sd += __shfl_xor(sd, o);
        pd += __shfl_xor(pd, o);
    }
    if (lane == 0) {
        float rs  = rowsum[row];
        float val = rs - __expf(INV_T * sd) + __expf(INV_T * pd);
        float lse = logf(val);
        atomicAdd(lossacc, lse - INV_T * pd);
    }
}

__global__ void k_final(const float* __restrict__ lossacc, float* __restrict__ out)
{
    out[0] = lossacc[0] * (1.0f / (float)M_ROWS);
}

// ---------------------------------------------------------------------------
extern "C" void kernel_launch(void* const* d_in, const int* in_sizes, int n_in,
                              void* d_out, int out_size, void* d_ws, size_t ws_size,
                              hipStream_t stream)
{
    const float* zi = (const float*)d_in[0];
    const float* zj = (const float*)d_in[1];

    float* rowsum  = (float*)d_ws;                               // 8192 f32
    float* lossacc = rowsum + M_ROWS;                            // 1 f32
    __hip_bfloat16* zb = (__hip_bfloat16*)((char*)d_ws + 65536); // 8192x128 bf16

    k_normalize<<<dim3(M_ROWS * 64 / 256), 256, 0, stream>>>(zi, zj, zb, rowsum, lossacc);
    k_simsum<<<dim3(64, 64), dim3(256), 0, stream>>>(zb, rowsum);
    k_rowloss<<<dim3(M_ROWS * 64 / 256), 256, 0, stream>>>(zb, rowsum, lossacc);
    k_final<<<1, 1, 0, stream>>>(lossacc, (float*)d_out);
}

// Round 2
// 65.213 us; speedup vs baseline: 2.6123x; 2.6123x over previous
//
#include <hip/hip_runtime.h>
#include <hip/hip_bf16.h>

#define M_ROWS 8192
#define HALF_N 4096
#define D 128
#define INV_T 2.0f   // 1 / temperature(0.5)

typedef __attribute__((ext_vector_type(4))) float f32x4;
typedef __attribute__((ext_vector_type(8))) short bf16x8;
typedef unsigned int u32;
typedef __attribute__((ext_vector_type(4))) u32 u32x4;

// ---------------------------------------------------------------------------
// Kernel A: L2-normalize rows (fp32 in, bf16 out), zero rowsum accumulator.
// One wave (64 lanes) per row; lane handles 2 of the 128 elements.
// ---------------------------------------------------------------------------
__global__ __launch_bounds__(256) void k_normalize(
    const float* __restrict__ zi, const float* __restrict__ zj,
    __hip_bfloat16* __restrict__ zb, float* __restrict__ rowsum)
{
    int t = blockIdx.x * 256 + threadIdx.x;
    if (t < M_ROWS) rowsum[t] = 0.0f;   // re-init every launch (ws not re-poisoned)

    int row  = t >> 6;
    int lane = t & 63;
    const float* src = (row < HALF_N) ? (zi + (size_t)row * D)
                                      : (zj + (size_t)(row - HALF_N) * D);
    float2 v = *(const float2*)(src + lane * 2);
    float ss = v.x * v.x + v.y * v.y;
    #pragma unroll
    for (int o = 32; o >= 1; o >>= 1) ss += __shfl_xor(ss, o);
    float scale = 1.0f / fmaxf(sqrtf(ss), 1e-12f);

    __hip_bfloat162 o2;
    o2.x = __float2bfloat16(v.x * scale);
    o2.y = __float2bfloat16(v.y * scale);
    *(__hip_bfloat162*)(zb + (size_t)row * D + lane * 2) = o2;
}

// ---------------------------------------------------------------------------
// Kernel B: for each 128x128 tile of sim = (zb zb^T)/T, accumulate
// rowsum[i] += sum_j exp(sim[i][j]) via fp32 atomics (spread over 8192
// addresses, 64 contenders each). Diagonal included (subtracted in kernel C).
// 256 threads = 4 waves; wave w owns rows [32w, 32w+32) x all 128 cols.
// LDS: A,B tiles 32KB each, XOR-swizzled 16B slots to kill bank conflicts.
// ---------------------------------------------------------------------------
__global__ __launch_bounds__(256) void k_simsum(
    const __hip_bfloat16* __restrict__ zb, float* __restrict__ rowsum)
{
    __shared__ u32x4 smem[4096];            // 64 KiB
    char* sA = (char*)smem;                 // [128 rows][256 B]
    char* sB = (char*)(smem + 2048);

    const int ibase = blockIdx.y * 128;
    const int jbase = blockIdx.x * 128;
    const int tid   = threadIdx.x;

    // Stage both tiles: 2048 chunks of 16B each per tile; swizzle slot ^= row&7.
    #pragma unroll
    for (int it = 0; it < 8; ++it) {
        int c = it * 256 + tid;
        int row = c >> 4, slot = c & 15;
        int dst = row * 256 + ((slot ^ (row & 7)) << 4);
        u32x4 va = *(const u32x4*)(zb + (size_t)(ibase + row) * D + slot * 8);
        *(u32x4*)(sA + dst) = va;
        u32x4 vb = *(const u32x4*)(zb + (size_t)(jbase + row) * D + slot * 8);
        *(u32x4*)(sB + dst) = vb;
    }
    __syncthreads();

    const int wv = tid >> 6, lane = tid & 63;
    const int lr = lane & 15, lg = lane >> 4;
    const int rbase = wv * 32;

    f32x4 acc[2][8];
    #pragma unroll
    for (int m = 0; m < 2; ++m)
        #pragma unroll
        for (int n = 0; n < 8; ++n) acc[m][n] = (f32x4){0.f, 0.f, 0.f, 0.f};

    #pragma unroll
    for (int ks = 0; ks < 4; ++ks) {
        int rowA0 = rbase + lr;
        int rowA1 = rbase + 16 + lr;
        bf16x8 a0 = *(const bf16x8*)(sA + rowA0 * 256 + (((ks * 4 + lg) ^ (rowA0 & 7)) << 4));
        bf16x8 a1 = *(const bf16x8*)(sA + rowA1 * 256 + (((ks * 4 + lg) ^ (rowA1 & 7)) << 4));
        #pragma unroll
        for (int n = 0; n < 8; ++n) {
            int rowB = n * 16 + lr;
            bf16x8 b = *(const bf16x8*)(sB + rowB * 256 + (((ks * 4 + lg) ^ (rowB & 7)) << 4));
            acc[0][n] = __builtin_amdgcn_mfma_f32_16x16x32_bf16(a0, b, acc[0][n], 0, 0, 0);
            acc[1][n] = __builtin_amdgcn_mfma_f32_16x16x32_bf16(a1, b, acc[1][n], 0, 0, 0);
        }
    }

    // Epilogue: exp(2*dot), reduce over 16 col-lanes, one atomic per row.
    #pragma unroll
    for (int m = 0; m < 2; ++m) {
        #pragma unroll
        for (int r = 0; r < 4; ++r) {
            float e = 0.f;
            #pragma unroll
            for (int n = 0; n < 8; ++n) e += __expf(INV_T * acc[m][n][r]);
            e += __shfl_xor(e, 1);
            e += __shfl_xor(e, 2);
            e += __shfl_xor(e, 4);
            e += __shfl_xor(e, 8);
            if (lr == 0) {
                int row = ibase + rbase + m * 16 + lg * 4 + r;
                atomicAdd(&rowsum[row], e);
            }
        }
    }
}

// ---------------------------------------------------------------------------
// Kernel C: per row, recompute self-dot and positive-pair dot (fp32 from
// bf16), lse = log(rowsum - exp(2*self) + exp(2*pos)), write lse - pos
// to rowloss[row]. One wave per row; NO global atomics.
// ---------------------------------------------------------------------------
__global__ __launch_bounds__(256) void k_rowloss(
    const __hip_bfloat16* __restrict__ zb, const float* __restrict__ rowsum,
    float* __restrict__ rowloss)
{
    int t = blockIdx.x * 256 + threadIdx.x;
    int row = t >> 6, lane = t & 63;
    int pair = row ^ HALF_N;

    __hip_bfloat162 av = *(const __hip_bfloat162*)(zb + (size_t)row  * D + lane * 2);
    __hip_bfloat162 bv = *(const __hip_bfloat162*)(zb + (size_t)pair * D + lane * 2);
    float ax = __bfloat162float(av.x), ay = __bfloat162float(av.y);
    float bx = __bfloat162float(bv.x), by = __bfloat162float(bv.y);
    float sd = ax * ax + ay * ay;
    float pd = ax * bx + ay * by;
    #pragma unroll
    for (int o = 32; o >= 1; o >>= 1) {
        sd += __shfl_xor(sd, o);
        pd += __shfl_xor(pd, o);
    }
    if (lane == 0) {
        float rs  = rowsum[row];
        float val = rs - __expf(INV_T * sd) + __expf(INV_T * pd);
        rowloss[row] = logf(val) - INV_T * pd;
    }
}

// ---------------------------------------------------------------------------
// Kernel D: single-block tree reduction of rowloss[8192] -> mean.
// ---------------------------------------------------------------------------
__global__ __launch_bounds__(1024) void k_reduce(
    const float* __restrict__ rowloss, float* __restrict__ out)
{
    __shared__ float sm[16];
    int tid = threadIdx.x;
    float s = 0.f;
    #pragma unroll
    for (int i = 0; i < M_ROWS / 1024; ++i) s += rowloss[i * 1024 + tid];
    #pragma unroll
    for (int o = 32; o >= 1; o >>= 1) s += __shfl_xor(s, o);
    if ((tid & 63) == 0) sm[tid >> 6] = s;
    __syncthreads();
    if (tid == 0) {
        float tot = 0.f;
        #pragma unroll
        for (int w = 0; w < 16; ++w) tot += sm[w];
        out[0] = tot * (1.0f / (float)M_ROWS);
    }
}

// ---------------------------------------------------------------------------
extern "C" void kernel_launch(void* const* d_in, const int* in_sizes, int n_in,
                              void* d_out, int out_size, void* d_ws, size_t ws_size,
                              hipStream_t stream)
{
    const float* zi = (const float*)d_in[0];
    const float* zj = (const float*)d_in[1];

    float* rowsum  = (float*)d_ws;                               // 8192 f32
    float* rowloss = rowsum + M_ROWS;                            // 8192 f32
    __hip_bfloat16* zb = (__hip_bfloat16*)((char*)d_ws + 65536); // 8192x128 bf16

    k_normalize<<<dim3(M_ROWS * 64 / 256), 256, 0, stream>>>(zi, zj, zb, rowsum);
    k_simsum<<<dim3(64, 64), dim3(256), 0, stream>>>(zb, rowsum);
    k_rowloss<<<dim3(M_ROWS * 64 / 256), 256, 0, stream>>>(zb, rowsum, rowloss);
    k_reduce<<<dim3(1), dim3(1024), 0, stream>>>(rowloss, (float*)d_out);
}